// Round 15
// baseline (501.034 us; speedup 1.0000x reference)
//
#include <hip/hip_runtime.h>
#include <hip/hip_bf16.h>

typedef __attribute__((ext_vector_type(4))) float f32x4;
typedef __attribute__((ext_vector_type(8))) __bf16 bf16x8;
typedef __attribute__((ext_vector_type(4))) unsigned int u32x4;

// B=32, S=4096, E=A=512.
// out = [weighted (32*512), prob (32*4096)] fp32, total 147456.

__device__ __forceinline__ float lo_bf(unsigned int u) {
  return __builtin_bit_cast(float, u << 16);
}
__device__ __forceinline__ float hi_bf(unsigned int u) {
  return __builtin_bit_cast(float, u & 0xffff0000u);
}

__device__ __forceinline__ void barrier_lgkm() {
  asm volatile("s_waitcnt lgkmcnt(0)" ::: "memory");
  __builtin_amdgcn_s_barrier();
  asm volatile("" ::: "memory");
}

// ---------- prep 1: wave-contiguous A-fragment (W^T) layout ----------
// Wf[((grp*16 + kb)*4 + nt4)*64 + lane][j] =
//   bf16(W_enc[kb*32 + (lane>>4)*8 + j][(grp*4 + nt4)*16 + (lane&15)])
__global__ void prep_w(const float* __restrict__ W_enc, unsigned short* __restrict__ Wf) {
  int idx = blockIdx.x * 256 + threadIdx.x;   // 0..32767
  int lane = idx & 63;
  int g = idx >> 6;
  int nt = g & 3, kb = (g >> 2) & 15, w = g >> 6;
  int n = (w * 4 + nt) * 16 + (lane & 15);
  int k0 = kb * 32 + (lane >> 4) * 8;
  unsigned short* dst = Wf + idx * 8;
  #pragma unroll
  for (int j = 0; j < 8; ++j) {
    float f = W_enc[(k0 + j) * 512 + n];
    dst[j] = __builtin_bit_cast(unsigned short, (__bf16)f);
  }
}

// ---------- prep 2 (k-split x4) ----------
__global__ void prep_c(const float* __restrict__ dec_h, const float* __restrict__ W_dec,
                       const float* __restrict__ b_dec, const float* __restrict__ b_enc,
                       float* __restrict__ cpart) {
  int b = blockIdx.x >> 2, j = blockIdx.x & 3;
  int a = threadIdx.x;                        // 512 threads
  const float* dh = dec_h + b * 512 + j * 128;
  const float* wd = W_dec + (j * 128) * 512 + a;
  float s = (j == 0) ? (b_dec[a] + b_enc[a]) : 0.f;
  #pragma unroll 8
  for (int k = 0; k < 128; ++k) s += dh[k] * wd[k * 512];
  cpart[j * 16384 + b * 512 + a] = s;
}

// ---------- main: 256 blocks x 512 thr. Waves 0-3 compute (nt=8, acc[8][4] AGPR),
// ---------- waves 4-7 stage. 8 chunks/block, 2 lgkm-barrier windows.
// ---------- DS-diet: input tile read 4x (256 b128/chunk) instead of 8x. ----------
// (512,1): 2 waves/SIMD -> 256-reg unified budget (compute needs ~198, stage ~213).
__global__ __launch_bounds__(512, 1) void attn_main(
    const float* __restrict__ input, const unsigned short* __restrict__ Wf,
    const float* __restrict__ cpart, const float* __restrict__ w_att,
    float* __restrict__ att_out, float* __restrict__ m_out, float* __restrict__ pw_out) {
  __shared__ u32x4 A4[8192];                 // 2 x (64 rows x 512 bf16), XOR-swizzled (128 KB)
  __shared__ float c_lds[512];
  __shared__ float w_lds[512];
  __shared__ float red[4][64];               // logit partials (4 compute waves)
  __shared__ float red2[4 * 8 * 72];         // pw partials [w][q][72-pad lanes] (9.2 KB)

  char* Al = (char*)A4;
  const int tid = threadIdx.x;
  const int wave = tid >> 6, lane = tid & 63;
  const int l15 = lane & 15, l4 = lane >> 4;
  const int blk = blockIdx.x;                // 256 blocks, 1 per CU
  const int ci0 = blk * 8;                   // 8 chunks of 64 rows
  const int b = ci0 >> 6;                    // batch
  const bool is_stage = wave >= 4;
  const int st = tid & 255;                  // stage thread id 0..255

  float4 g[8][2];                            // 8 16B-units in flight (64 VGPR, stage waves)

  // issue 8 units (unit = 16B = 8 floats) of half h of chunk ci
  auto ISSUE8 = [&](int ci, int h) {
    const float* base = input + (long)ci * 32768;
    #pragma unroll
    for (int j = 0; j < 8; ++j) {
      int idx = st + (h * 8 + j) * 256;      // 0..4095
      int row = idx >> 6, c32 = idx & 63;
      const float4* s4 = (const float4*)(base + row * 512 + c32 * 8);
      g[j][0] = s4[0];
      g[j][1] = s4[1];
    }
  };
  auto WRITE8 = [&](int bufsel, int h) {
    char* dst = Al + bufsel * 65536;
    #pragma unroll
    for (int j = 0; j < 8; ++j) {
      int idx = st + (h * 8 + j) * 256;
      int row = idx >> 6, c32 = idx & 63;
      bf16x8 v;
      v[0] = (__bf16)g[j][0].x; v[1] = (__bf16)g[j][0].y;
      v[2] = (__bf16)g[j][0].z; v[3] = (__bf16)g[j][0].w;
      v[4] = (__bf16)g[j][1].x; v[5] = (__bf16)g[j][1].y;
      v[6] = (__bf16)g[j][1].z; v[7] = (__bf16)g[j][1].w;
      *(bf16x8*)(dst + row * 1024 + ((c32 * 16) ^ ((row & 7) << 4))) = v;
    }
  };

  // ---- prologue ----
  if (!is_stage) {
    #pragma unroll
    for (int q = 0; q < 2; ++q) {
      int t = tid + q * 256;
      c_lds[t] = cpart[b * 512 + t] + cpart[16384 + b * 512 + t]
               + cpart[32768 + b * 512 + t] + cpart[49152 + b * 512 + t];
      w_lds[t] = w_att[t];
    }
  } else {
    ISSUE8(ci0, 0); WRITE8(0, 0);
    ISSUE8(ci0, 1); WRITE8(0, 1);
  }
  barrier_lgkm();

  const bf16x8* Wfp = (const bf16x8*)Wf;
  // wave owns ntiles wave*8..wave*8+7 -> fragment groups 2*wave, 2*wave+1.
  // frag index: wave*128 + (nt>>2)*64 + kb*4 + (nt&3)
  const bf16x8* wb = Wfp + (wave * 128) * 64 + lane;

  for (int i = 0; i < 8; ++i) {
    const int ci = ci0 + i;
    const char* Ab = Al + (i & 1) * 65536;

    // ====== phase 1: pw-store(prev) + K-loop + epilogue || ISSUE h0,WRITE h0,ISSUE h1 ======
    if (!is_stage) {
      if (i >= 1) {                          // store pw(chunk i-1): 256 threads x 2 cols
        #pragma unroll
        for (int q2 = 0; q2 < 2; ++q2) {
          int t = st + q2 * 256;
          int lw = t >> 3, q = t & 7;
          float s = red2[(0 * 8 + q) * 72 + lw] + red2[(1 * 8 + q) * 72 + lw]
                  + red2[(2 * 8 + q) * 72 + lw] + red2[(3 * 8 + q) * 72 + lw];
          pw_out[(ci - 1) * 512 + lw * 8 + q] = s;
        }
      }
      f32x4 acc[8][4];                       // [nt][st4] -> 128 AGPRs
      #pragma unroll
      for (int nt = 0; nt < 8; ++nt)
        #pragma unroll
        for (int s4 = 0; s4 < 4; ++s4) {
          f32x4 z = {0.f, 0.f, 0.f, 0.f};
          acc[nt][s4] = z;
        }
      #pragma unroll
      for (int kb = 0; kb < 16; ++kb) {
        bf16x8 av[8];
        #pragma unroll
        for (int nt = 0; nt < 8; ++nt)
          av[nt] = wb[((nt >> 2) * 64 + kb * 4 + (nt & 3)) * 64];
        __builtin_amdgcn_s_setprio(1);
        #pragma unroll
        for (int s4 = 0; s4 < 4; ++s4) {
          int row = s4 * 16 + l15;
          bf16x8 xf = *(const bf16x8*)(Ab + row * 1024 + (((kb * 64) + l4 * 16) ^ ((row & 7) << 4)));
          #pragma unroll
          for (int nt = 0; nt < 8; ++nt)
            acc[nt][s4] = __builtin_amdgcn_mfma_f32_16x16x32_bf16(av[nt], xf, acc[nt][s4], 0, 0, 0);
        }
        __builtin_amdgcn_s_setprio(0);
      }
      // epilogue: n-sum in-lane over (nt,r), cross-lane over l4 only
      float attp[4] = {0.f, 0.f, 0.f, 0.f};
      #pragma unroll
      for (int nt = 0; nt < 8; ++nt) {
        #pragma unroll
        for (int r = 0; r < 4; ++r) {
          int n = (wave * 8 + nt) * 16 + l4 * 4 + r;
          float cc = c_lds[n], ww = w_lds[n];
          #pragma unroll
          for (int s4 = 0; s4 < 4; ++s4)
            attp[s4] += fmaxf(acc[nt][s4][r] + cc, 0.f) * ww;
        }
      }
      #pragma unroll
      for (int s4 = 0; s4 < 4; ++s4) {
        attp[s4] += __shfl_xor(attp[s4], 16, 64);
        attp[s4] += __shfl_xor(attp[s4], 32, 64);
      }
      if (l4 == 0) {
        #pragma unroll
        for (int s4 = 0; s4 < 4; ++s4)
          red[wave][s4 * 16 + l15] = attp[s4];
      }
    } else if (i < 7) {
      ISSUE8(ci + 1, 0);
      WRITE8((i + 1) & 1, 0);                // waits only h0's loads
      ISSUE8(ci + 1, 1);                     // h1 loads fly across the barrier
    }
    barrier_lgkm();

    // ============ phase 2: softmax + pw partials  ||  WRITE h1 ============
    if (!is_stage) {
      float av = red[0][lane] + red[1][lane] + red[2][lane] + red[3][lane];
      float m = av;
      #pragma unroll
      for (int off = 32; off >= 1; off >>= 1) m = fmaxf(m, __shfl_xor(m, off, 64));
      float p = expf(av - m);                // row = lane
      if (wave == 0) {
        att_out[b * 4096 + (ci & 63) * 64 + lane] = av;  // b_att omitted: cancels in softmax
        if (lane == 0) m_out[ci] = m;
      }
      // pw: wave owns rows wave*16..+15; lane reads full permuted row slice (conflict-free)
      float acc8[8] = {0.f, 0.f, 0.f, 0.f, 0.f, 0.f, 0.f, 0.f};
      #pragma unroll
      for (int j = 0; j < 16; ++j) {
        int s = wave * 16 + j;
        float ps = __shfl(p, s, 64);
        u32x4 u = *(const u32x4*)(Ab + s * 1024 + ((lane * 16) ^ ((s & 7) << 4)));
        acc8[0] += ps * lo_bf(u[0]); acc8[1] += ps * hi_bf(u[0]);
        acc8[2] += ps * lo_bf(u[1]); acc8[3] += ps * hi_bf(u[1]);
        acc8[4] += ps * lo_bf(u[2]); acc8[5] += ps * hi_bf(u[2]);
        acc8[6] += ps * lo_bf(u[3]); acc8[7] += ps * hi_bf(u[3]);
      }
      #pragma unroll
      for (int q = 0; q < 8; ++q)
        red2[(wave * 8 + q) * 72 + lane] = acc8[q];      // cols lane*8+q
    } else if (i < 7) {
      WRITE8((i + 1) & 1, 1);
    }
    barrier_lgkm();
  }

  // final pw store (chunk ci0+7), all 8 waves
  if (tid < 512) {
    int lw = tid >> 3, q = tid & 7;
    float s = red2[(0 * 8 + q) * 72 + lw] + red2[(1 * 8 + q) * 72 + lw]
            + red2[(2 * 8 + q) * 72 + lw] + red2[(3 * 8 + q) * 72 + lw];
    pw_out[(ci0 + 7) * 512 + lw * 8 + q] = s;
  }
}

// ---------- finalize: per-batch global softmax + rescaled partial-sum reduction ----------
__global__ void finalize(const float* __restrict__ att, const float* __restrict__ m_blk,
                         const float* __restrict__ pw, float* __restrict__ out) {
  const int bg = blockIdx.x;                 // 128 blocks = 32 b x 4 groups
  const int b = bg >> 2, g = bg & 3;
  const int tid = threadIdx.x;               // 256
  const int wave = tid >> 6, lane = tid & 63;
  __shared__ float wred[4];
  __shared__ float zred[4];
  __shared__ float fac[64];

  float v[16];
  float mx = -3.4e38f;
  #pragma unroll
  for (int i = 0; i < 16; ++i) {
    v[i] = att[b * 4096 + i * 256 + tid];
    mx = fmaxf(mx, v[i]);
  }
  #pragma unroll
  for (int off = 32; off >= 1; off >>= 1) mx = fmaxf(mx, __shfl_xor(mx, off, 64));
  if (lane == 0) wred[wave] = mx;
  __syncthreads();
  mx = fmaxf(fmaxf(wred[0], wred[1]), fmaxf(wred[2], wred[3]));

  float z = 0.f;
  #pragma unroll
  for (int i = 0; i < 16; ++i) { v[i] = expf(v[i] - mx); z += v[i]; }
  #pragma unroll
  for (int off = 32; off >= 1; off >>= 1) z += __shfl_xor(z, off, 64);
  if (lane == 0) zred[wave] = z;
  __syncthreads();
  z = zred[0] + zred[1] + zred[2] + zred[3];
  float invZ = 1.f / z;

  #pragma unroll
  for (int i = 0; i < 4; ++i) {
    int ii = g * 4 + i;
    out[16384 + b * 4096 + ii * 256 + tid] = v[ii] * invZ;   // prob (this block's quarter)
  }

  if (tid < 64) fac[tid] = expf(m_blk[b * 64 + tid] - mx) * invZ;
  __syncthreads();

  int col = g * 128 + (tid >> 1);
  int h = tid & 1;
  float w0 = 0.f;
  #pragma unroll 8
  for (int s = h * 32; s < h * 32 + 32; ++s)
    w0 += fac[s] * pw[(b * 64 + s) * 512 + col];
  w0 += __shfl_xor(w0, 1, 64);
  if (h == 0) out[b * 512 + col] = w0;                       // weighted
}

extern "C" void kernel_launch(void* const* d_in, const int* in_sizes, int n_in,
                              void* d_out, int out_size, void* d_ws, size_t ws_size,
                              hipStream_t stream) {
  const float* input = (const float*)d_in[0];
  const float* dec_h = (const float*)d_in[1];
  const float* W_enc = (const float*)d_in[2];
  const float* b_enc = (const float*)d_in[3];
  const float* W_dec = (const float*)d_in[4];
  const float* b_dec = (const float*)d_in[5];
  const float* w_att = (const float*)d_in[6];
  // d_in[7] = b_att: constant shift of logits, cancels in softmax.
  float* out = (float*)d_out;

  char* ws = (char*)d_ws;
  unsigned short* Wf = (unsigned short*)(ws);           // 512 KB  A-fragment-ordered bf16 W_enc^T
  float* cpart = (float*)(ws + 524288);                 // 256 KB  dec_att partials [4][32][512]
  float* att   = (float*)(ws + 786432);                 // 512 KB  logits [32][4096]
  float* m_b   = (float*)(ws + 1310720);                // 8 KB    per-chunk max [2048]
  float* pw    = (float*)(ws + 1318912);                // 4 MB    partial weighted [2048][512]

  hipLaunchKernelGGL(prep_w, dim3(128), dim3(256), 0, stream, W_enc, Wf);
  hipLaunchKernelGGL(prep_c, dim3(128), dim3(512), 0, stream, dec_h, W_dec, b_dec, b_enc, cpart);
  hipLaunchKernelGGL(attn_main, dim3(256), dim3(512), 0, stream, input, Wf, cpart, w_att, att, m_b, pw);
  hipLaunchKernelGGL(finalize, dim3(128), dim3(256), 0, stream, att, m_b, pw, out);
}

// Round 16
// 311.592 us; speedup vs baseline: 1.6080x; 1.6080x over previous
//
#include <hip/hip_runtime.h>
#include <hip/hip_bf16.h>

typedef __attribute__((ext_vector_type(4))) float f32x4;
typedef __attribute__((ext_vector_type(8))) __bf16 bf16x8;
typedef __attribute__((ext_vector_type(4))) unsigned int u32x4;

// B=32, S=4096, E=A=512.
// out = [weighted (32*512), prob (32*4096)] fp32, total 147456.

__device__ __forceinline__ float lo_bf(unsigned int u) {
  return __builtin_bit_cast(float, u << 16);
}
__device__ __forceinline__ float hi_bf(unsigned int u) {
  return __builtin_bit_cast(float, u & 0xffff0000u);
}

// Raw barrier: drain LDS ops only — vmcnt (global loads/stores) stays in flight.
__device__ __forceinline__ void barrier_lgkm() {
  asm volatile("s_waitcnt lgkmcnt(0)" ::: "memory");
  __builtin_amdgcn_s_barrier();
  asm volatile("" ::: "memory");
}

// ---------- prep 1: wave-contiguous A-fragment (W^T) layout ----------
// Wf[(((w*16 + kb)*4 + nt)*64 + lane)*8 + j] =
//   bf16(W_enc[kb*32 + (lane>>4)*8 + j][(w*4 + nt)*16 + (lane&15)])
__global__ void prep_w(const float* __restrict__ W_enc, unsigned short* __restrict__ Wf) {
  int idx = blockIdx.x * 256 + threadIdx.x;   // 0..32767
  int lane = idx & 63;
  int g = idx >> 6;
  int nt = g & 3, kb = (g >> 2) & 15, w = g >> 6;
  int n = (w * 4 + nt) * 16 + (lane & 15);
  int k0 = kb * 32 + (lane >> 4) * 8;
  unsigned short* dst = Wf + idx * 8;
  #pragma unroll
  for (int j = 0; j < 8; ++j) {
    float f = W_enc[(k0 + j) * 512 + n];
    dst[j] = __builtin_bit_cast(unsigned short, (__bf16)f);
  }
}

// ---------- prep 2 (k-split x4): cpart[j][b][a] = partial dec_h@W_dec (+biases in j==0) ----------
__global__ void prep_c(const float* __restrict__ dec_h, const float* __restrict__ W_dec,
                       const float* __restrict__ b_dec, const float* __restrict__ b_enc,
                       float* __restrict__ cpart) {
  int b = blockIdx.x >> 2, j = blockIdx.x & 3;
  int a = threadIdx.x;                        // 512 threads
  const float* dh = dec_h + b * 512 + j * 128;
  const float* wd = W_dec + (j * 128) * 512 + a;
  float s = (j == 0) ? (b_dec[a] + b_enc[a]) : 0.f;
  #pragma unroll 8
  for (int k = 0; k < 128; ++k) s += dh[k] * wd[k * 512];
  cpart[j * 16384 + b * 512 + a] = s;
}

// ---------- main: 1024 thr / 16 waves / 1 block/CU. Waves 0-7 compute, 8-15 stage.
// ---------- Round-9 champion structure. (1024,1): min 1 block/CU -> compiler may
// ---------- allocate up to 512 regs/wave (vs the 64-V cap that (1024,4) forced),
// ---------- letting it hoist K-loop W-fragment loads across unrolled iterations. ----------
__global__ __launch_bounds__(1024, 1) void attn_main(
    const float* __restrict__ input, const unsigned short* __restrict__ Wf,
    const float* __restrict__ cpart, const float* __restrict__ w_att,
    float* __restrict__ att_out, float* __restrict__ m_out, float* __restrict__ pw_out) {
  __shared__ u32x4 A4[8192];                 // 2 x (64 rows x 512 bf16), XOR-swizzled (128 KB)
  __shared__ float c_lds[512];
  __shared__ float w_lds[512];
  __shared__ float red[8][64];               // logit partials per wave
  __shared__ float red2[8 * 8 * 72];         // pw partials [w][q][72-padded lanes] (18.4 KB)

  char* Al = (char*)A4;
  const int tid = threadIdx.x;
  const int wave = tid >> 6, lane = tid & 63;
  const int l15 = lane & 15, l4 = lane >> 4;
  const int blk = blockIdx.x;                // 256 blocks, 1 per CU
  const int ci0 = blk * 8;                   // 8 chunks of 64 rows per block
  const int b = ci0 >> 6;                    // batch (all 8 chunks in same batch)
  const bool is_stage = wave >= 8;
  const int st_id = tid & 511;

  float4 g[4][2];                            // staging regs (32 VGPR, stage waves only)

  auto STAGE_HALF = [&](int ci, int bufsel, int half) {
    const float* base = input + (long)ci * 32768;
    char* dst = Al + bufsel * 65536;
    #pragma unroll
    for (int j = 0; j < 4; ++j) {
      int ch = st_id + j * 512;
      int row = (ch >> 6) + half * 32, c32 = ch & 63;
      const float4* s4 = (const float4*)(base + row * 512 + c32 * 8);
      g[j][0] = s4[0];
      g[j][1] = s4[1];
    }
    #pragma unroll
    for (int j = 0; j < 4; ++j) {
      int ch = st_id + j * 512;
      int row = (ch >> 6) + half * 32, c32 = ch & 63;
      bf16x8 v;
      v[0] = (__bf16)g[j][0].x; v[1] = (__bf16)g[j][0].y;
      v[2] = (__bf16)g[j][0].z; v[3] = (__bf16)g[j][0].w;
      v[4] = (__bf16)g[j][1].x; v[5] = (__bf16)g[j][1].y;
      v[6] = (__bf16)g[j][1].z; v[7] = (__bf16)g[j][1].w;
      *(bf16x8*)(dst + row * 1024 + ((c32 * 16) ^ ((row & 7) << 4))) = v;
    }
  };

  // ---- prologue ----
  if (!is_stage) {
    c_lds[tid] = cpart[b * 512 + tid] + cpart[16384 + b * 512 + tid]
               + cpart[32768 + b * 512 + tid] + cpart[49152 + b * 512 + tid];
    w_lds[tid] = w_att[tid];
  } else {
    STAGE_HALF(ci0, 0, 0);
    STAGE_HALF(ci0, 0, 1);
  }
  barrier_lgkm();

  const bf16x8* Wfp = (const bf16x8*)Wf;

  for (int i = 0; i < 8; ++i) {
    const int ci = ci0 + i;
    const char* Ab = Al + (i & 1) * 65536;

    // ============ phase 1: K-loop + epilogue  ||  stage h0 + pw-store(i-1) ============
    if (!is_stage) {
      f32x4 acc[4][4];                       // [nt][st]: D rows=n, cols=seq
      #pragma unroll
      for (int nt = 0; nt < 4; ++nt)
        #pragma unroll
        for (int st = 0; st < 4; ++st) {
          f32x4 z = {0.f, 0.f, 0.f, 0.f};
          acc[nt][st] = z;
        }
      const bf16x8* wb = Wfp + (wave * 64) * 64 + lane;   // wave's 64KB linear region
      #pragma unroll
      for (int kb = 0; kb < 16; ++kb) {
        bf16x8 av4[4];
        #pragma unroll
        for (int nt = 0; nt < 4; ++nt)
          av4[nt] = wb[(kb * 4 + nt) * 64];  // 4KB contiguous per kb
        __builtin_amdgcn_s_setprio(1);
        #pragma unroll
        for (int st = 0; st < 4; ++st) {
          int row = st * 16 + l15;
          bf16x8 xf = *(const bf16x8*)(Ab + row * 1024 + (((kb * 64) + l4 * 16) ^ ((row & 7) << 4)));
          #pragma unroll
          for (int nt = 0; nt < 4; ++nt)
            acc[nt][st] = __builtin_amdgcn_mfma_f32_16x16x32_bf16(av4[nt], xf, acc[nt][st], 0, 0, 0);
        }
        __builtin_amdgcn_s_setprio(0);
      }
      // epilogue: att partial over this wave's 64 n; n-sum in-lane over (nt,r), cross-lane over l4
      float attp[4] = {0.f, 0.f, 0.f, 0.f};
      #pragma unroll
      for (int nt = 0; nt < 4; ++nt) {
        #pragma unroll
        for (int r = 0; r < 4; ++r) {
          int n = (wave * 4 + nt) * 16 + l4 * 4 + r;
          float cc = c_lds[n], ww = w_lds[n];
          #pragma unroll
          for (int st = 0; st < 4; ++st)
            attp[st] += fmaxf(acc[nt][st][r] + cc, 0.f) * ww;
        }
      }
      #pragma unroll
      for (int st = 0; st < 4; ++st) {
        attp[st] += __shfl_xor(attp[st], 16, 64);
        attp[st] += __shfl_xor(attp[st], 32, 64);
      }
      if (l4 == 0) {
        #pragma unroll
        for (int st = 0; st < 4; ++st)
          red[wave][st * 16 + l15] = attp[st];
      }
    } else {
      if (i < 7) STAGE_HALF(ci + 1, (i + 1) & 1, 0);
      if (i >= 1) {                          // combine + store pw(chunk i-1), off compute path
        int lw = st_id >> 3, q = st_id & 7;
        float s = 0.f;
        #pragma unroll
        for (int w = 0; w < 8; ++w) s += red2[(w * 8 + q) * 72 + lw];
        pw_out[(ci - 1) * 512 + lw * 8 + q] = s;
      }
    }
    barrier_lgkm();

    // ============ phase 2: softmax + pw partials  ||  stage h1 ============
    if (!is_stage) {
      float av = 0.f;
      #pragma unroll
      for (int cw = 0; cw < 8; ++cw) av += red[cw][lane];
      float m = av;
      #pragma unroll
      for (int off = 32; off >= 1; off >>= 1) m = fmaxf(m, __shfl_xor(m, off, 64));
      float p = expf(av - m);                // row = lane
      if (wave == 0) {
        att_out[b * 4096 + (ci & 63) * 64 + lane] = av;  // b_att omitted: cancels in softmax
        if (lane == 0) m_out[ci] = m;
      }
      // pw: wave w owns s-rows w*8..w*8+7; lane reads full permuted row slice (conflict-free)
      float acc8[8] = {0.f, 0.f, 0.f, 0.f, 0.f, 0.f, 0.f, 0.f};
      #pragma unroll
      for (int j = 0; j < 8; ++j) {
        int s = wave * 8 + j;
        float ps = __shfl(p, s, 64);
        u32x4 u = *(const u32x4*)(Ab + s * 1024 + ((lane * 16) ^ ((s & 7) << 4)));
        acc8[0] += ps * lo_bf(u[0]); acc8[1] += ps * hi_bf(u[0]);
        acc8[2] += ps * lo_bf(u[1]); acc8[3] += ps * hi_bf(u[1]);
        acc8[4] += ps * lo_bf(u[2]); acc8[5] += ps * hi_bf(u[2]);
        acc8[6] += ps * lo_bf(u[3]); acc8[7] += ps * hi_bf(u[3]);
      }
      #pragma unroll
      for (int q = 0; q < 8; ++q)
        red2[(wave * 8 + q) * 72 + lane] = acc8[q];      // cols lane*8+q, s-oct = wave
    } else if (i < 7) {
      STAGE_HALF(ci + 1, (i + 1) & 1, 1);
    }
    barrier_lgkm();
  }

  // final pw store (chunk ci0+7)
  if (tid < 512) {
    int lw = tid >> 3, q = tid & 7;
    float s = 0.f;
    #pragma unroll
    for (int w = 0; w < 8; ++w) s += red2[(w * 8 + q) * 72 + lw];
    pw_out[(ci0 + 7) * 512 + lw * 8 + q] = s;
  }
}

// ---------- finalize: per-batch global softmax + rescaled partial-sum reduction ----------
__global__ void finalize(const float* __restrict__ att, const float* __restrict__ m_blk,
                         const float* __restrict__ pw, float* __restrict__ out) {
  const int bg = blockIdx.x;                 // 128 blocks = 32 b x 4 groups
  const int b = bg >> 2, g = bg & 3;
  const int tid = threadIdx.x;               // 256
  const int wave = tid >> 6, lane = tid & 63;
  __shared__ float wred[4];
  __shared__ float zred[4];
  __shared__ float fac[64];

  float v[16];
  float mx = -3.4e38f;
  #pragma unroll
  for (int i = 0; i < 16; ++i) {
    v[i] = att[b * 4096 + i * 256 + tid];
    mx = fmaxf(mx, v[i]);
  }
  #pragma unroll
  for (int off = 32; off >= 1; off >>= 1) mx = fmaxf(mx, __shfl_xor(mx, off, 64));
  if (lane == 0) wred[wave] = mx;
  __syncthreads();
  mx = fmaxf(fmaxf(wred[0], wred[1]), fmaxf(wred[2], wred[3]));

  float z = 0.f;
  #pragma unroll
  for (int i = 0; i < 16; ++i) { v[i] = expf(v[i] - mx); z += v[i]; }
  #pragma unroll
  for (int off = 32; off >= 1; off >>= 1) z += __shfl_xor(z, off, 64);
  if (lane == 0) zred[wave] = z;
  __syncthreads();
  z = zred[0] + zred[1] + zred[2] + zred[3];
  float invZ = 1.f / z;

  #pragma unroll
  for (int i = 0; i < 4; ++i) {
    int ii = g * 4 + i;
    out[16384 + b * 4096 + ii * 256 + tid] = v[ii] * invZ;   // prob (this block's quarter)
  }

  if (tid < 64) fac[tid] = expf(m_blk[b * 64 + tid] - mx) * invZ;
  __syncthreads();

  int col = g * 128 + (tid >> 1);
  int h = tid & 1;
  float w0 = 0.f;
  #pragma unroll 8
  for (int s = h * 32; s < h * 32 + 32; ++s)
    w0 += fac[s] * pw[(b * 64 + s) * 512 + col];
  w0 += __shfl_xor(w0, 1, 64);
  if (h == 0) out[b * 512 + col] = w0;                       // weighted
}

extern "C" void kernel_launch(void* const* d_in, const int* in_sizes, int n_in,
                              void* d_out, int out_size, void* d_ws, size_t ws_size,
                              hipStream_t stream) {
  const float* input = (const float*)d_in[0];
  const float* dec_h = (const float*)d_in[1];
  const float* W_enc = (const float*)d_in[2];
  const float* b_enc = (const float*)d_in[3];
  const float* W_dec = (const float*)d_in[4];
  const float* b_dec = (const float*)d_in[5];
  const float* w_att = (const float*)d_in[6];
  // d_in[7] = b_att: constant shift of logits, cancels in softmax.
  float* out = (float*)d_out;

  char* ws = (char*)d_ws;
  unsigned short* Wf = (unsigned short*)(ws);           // 512 KB  A-fragment-ordered bf16 W_enc^T
  float* cpart = (float*)(ws + 524288);                 // 256 KB  dec_att partials [4][32][512]
  float* att   = (float*)(ws + 786432);                 // 512 KB  logits [32][4096]
  float* m_b   = (float*)(ws + 1310720);                // 8 KB    per-chunk max [2048]
  float* pw    = (float*)(ws + 1318912);                // 4 MB    partial weighted [2048][512]

  hipLaunchKernelGGL(prep_w, dim3(128), dim3(256), 0, stream, W_enc, Wf);
  hipLaunchKernelGGL(prep_c, dim3(128), dim3(512), 0, stream, dec_h, W_dec, b_dec, b_enc, cpart);
  hipLaunchKernelGGL(attn_main, dim3(256), dim3(1024), 0, stream, input, Wf, cpart, w_att, att, m_b, pw);
  hipLaunchKernelGGL(finalize, dim3(128), dim3(256), 0, stream, att, m_b, pw, out);
}

// Round 17
// 136.687 us; speedup vs baseline: 3.6655x; 2.2796x over previous
//
#include <hip/hip_runtime.h>
#include <hip/hip_bf16.h>

typedef __attribute__((ext_vector_type(4))) float f32x4;
typedef __attribute__((ext_vector_type(16))) float f32x16;
typedef __attribute__((ext_vector_type(8))) __bf16 bf16x8;
typedef __attribute__((ext_vector_type(4))) unsigned int u32x4;

// B=32, S=4096, E=A=512.
// out = [weighted (32*512), prob (32*4096)] fp32, total 147456.

__device__ __forceinline__ float lo_bf(unsigned int u) {
  return __builtin_bit_cast(float, u << 16);
}
__device__ __forceinline__ float hi_bf(unsigned int u) {
  return __builtin_bit_cast(float, u & 0xffff0000u);
}

// Raw barrier: drain LDS ops only — vmcnt (global loads/stores) stays in flight.
__device__ __forceinline__ void barrier_lgkm() {
  asm volatile("s_waitcnt lgkmcnt(0)" ::: "memory");
  __builtin_amdgcn_s_barrier();
  asm volatile("" ::: "memory");
}

// ---------- prep 1: wave-contiguous A-fragment layout for 32x32x16 MFMA ----------
// frag f = wave*64 + kstep*2 + nt  (wave's 64 frags are linear = 64 KB region)
// Wf[(f*64 + lane)*8 + j] = bf16(W_enc[kstep*16 + (lane>>5)*8 + j][wave*64 + nt*32 + (lane&31)])
// A-operand mapping (32x32x16): m = lane&31, k = (lane>>5)*8 + j.
__global__ void prep_w(const float* __restrict__ W_enc, unsigned short* __restrict__ Wf) {
  int idx = blockIdx.x * 256 + threadIdx.x;   // 0..32767
  int lane = idx & 63;
  int f = idx >> 6;
  int w = f >> 6, rem = f & 63;
  int kstep = rem >> 1, nt = rem & 1;
  int n = w * 64 + nt * 32 + (lane & 31);
  int k0 = kstep * 16 + (lane >> 5) * 8;
  unsigned short* dst = Wf + idx * 8;
  #pragma unroll
  for (int j = 0; j < 8; ++j) {
    float v = W_enc[(k0 + j) * 512 + n];
    dst[j] = __builtin_bit_cast(unsigned short, (__bf16)v);
  }
}

// ---------- prep 2 (k-split x4): cpart[j][b][a] = partial dec_h@W_dec (+biases in j==0) ----------
__global__ void prep_c(const float* __restrict__ dec_h, const float* __restrict__ W_dec,
                       const float* __restrict__ b_dec, const float* __restrict__ b_enc,
                       float* __restrict__ cpart) {
  int b = blockIdx.x >> 2, j = blockIdx.x & 3;
  int a = threadIdx.x;                        // 512 threads
  const float* dh = dec_h + b * 512 + j * 128;
  const float* wd = W_dec + (j * 128) * 512 + a;
  float s = (j == 0) ? (b_dec[a] + b_enc[a]) : 0.f;
  #pragma unroll 8
  for (int k = 0; k < 128; ++k) s += dh[k] * wd[k * 512];
  cpart[j * 16384 + b * 512 + a] = s;
}

// ---------- main: 1024 thr / 16 waves / 1 block/CU. Waves 0-7 compute, 8-15 stage.
// ---------- Champion (R8) structure with 32x32x16 MFMA: half the MFMA instrs,
// ---------- half the live A-frag regs, 1-shfl epilogue. Fits the 64-VGPR wall. ----------
__global__ __launch_bounds__(1024, 4) void attn_main(
    const float* __restrict__ input, const unsigned short* __restrict__ Wf,
    const float* __restrict__ cpart, const float* __restrict__ w_att,
    float* __restrict__ att_out, float* __restrict__ m_out, float* __restrict__ pw_out) {
  __shared__ u32x4 A4[8192];                 // 2 x (64 rows x 512 bf16), XOR-swizzled (128 KB)
  __shared__ float c_lds[512];
  __shared__ float w_lds[512];
  __shared__ float red[8][64];               // logit partials per wave
  __shared__ float red2[8 * 8 * 72];         // pw partials [w][q][72-padded lanes] (18.4 KB)

  char* Al = (char*)A4;
  const int tid = threadIdx.x;
  const int wave = tid >> 6, lane = tid & 63;
  const int l31 = lane & 31, h = lane >> 5;
  const int blk = blockIdx.x;                // 256 blocks, 1 per CU
  const int ci0 = blk * 8;                   // 8 chunks of 64 rows per block
  const int b = ci0 >> 6;                    // batch (all 8 chunks in same batch)
  const bool is_stage = wave >= 8;
  const int st_id = tid & 511;

  float4 g[4][2];                            // staging regs (32 VGPR, stage waves only)

  auto STAGE_HALF = [&](int ci, int bufsel, int half) {
    const float* base = input + (long)ci * 32768;
    char* dst = Al + bufsel * 65536;
    #pragma unroll
    for (int j = 0; j < 4; ++j) {
      int ch = st_id + j * 512;
      int row = (ch >> 6) + half * 32, c32 = ch & 63;
      const float4* s4 = (const float4*)(base + row * 512 + c32 * 8);
      g[j][0] = s4[0];
      g[j][1] = s4[1];
    }
    #pragma unroll
    for (int j = 0; j < 4; ++j) {
      int ch = st_id + j * 512;
      int row = (ch >> 6) + half * 32, c32 = ch & 63;
      bf16x8 v;
      v[0] = (__bf16)g[j][0].x; v[1] = (__bf16)g[j][0].y;
      v[2] = (__bf16)g[j][0].z; v[3] = (__bf16)g[j][0].w;
      v[4] = (__bf16)g[j][1].x; v[5] = (__bf16)g[j][1].y;
      v[6] = (__bf16)g[j][1].z; v[7] = (__bf16)g[j][1].w;
      *(bf16x8*)(dst + row * 1024 + ((c32 * 16) ^ ((row & 7) << 4))) = v;
    }
  };

  // ---- prologue ----
  if (!is_stage) {
    c_lds[tid] = cpart[b * 512 + tid] + cpart[16384 + b * 512 + tid]
               + cpart[32768 + b * 512 + tid] + cpart[49152 + b * 512 + tid];
    w_lds[tid] = w_att[tid];
  } else {
    STAGE_HALF(ci0, 0, 0);
    STAGE_HALF(ci0, 0, 1);
  }
  barrier_lgkm();

  const bf16x8* Wfp = (const bf16x8*)Wf;

  for (int i = 0; i < 8; ++i) {
    const int ci = ci0 + i;
    const char* Ab = Al + (i & 1) * 65536;

    // ============ phase 1: K-loop + epilogue  ||  stage half 0 ============
    if (!is_stage) {
      f32x16 acc2[2][2];                     // [nt][st]: D rows=n (32), cols=seq (32); 64 AGPR
      #pragma unroll
      for (int nt = 0; nt < 2; ++nt)
        #pragma unroll
        for (int st = 0; st < 2; ++st)
          #pragma unroll
          for (int r = 0; r < 16; ++r)
            acc2[nt][st][r] = 0.f;
      const bf16x8* wb = Wfp + (wave * 64) * 64 + lane;   // wave's 64KB linear region
      #pragma unroll 4
      for (int kstep = 0; kstep < 32; ++kstep) {
        bf16x8 av[2];
        av[0] = wb[(kstep * 2 + 0) * 64];
        av[1] = wb[(kstep * 2 + 1) * 64];
        __builtin_amdgcn_s_setprio(1);
        #pragma unroll
        for (int st = 0; st < 2; ++st) {
          int row = st * 32 + l31;
          bf16x8 xf = *(const bf16x8*)(Ab + row * 1024 +
                        (((kstep * 32) + h * 16) ^ ((row & 7) << 4)));
          acc2[0][st] = __builtin_amdgcn_mfma_f32_32x32x16_bf16(av[0], xf, acc2[0][st], 0, 0, 0);
          acc2[1][st] = __builtin_amdgcn_mfma_f32_32x32x16_bf16(av[1], xf, acc2[1][st], 0, 0, 0);
        }
        __builtin_amdgcn_s_setprio(0);
      }
      // epilogue: att partial over this wave's 64 n.
      // D mapping: col(seq) = lane&31, row(n within 32-tile) = (reg&3)+8*(reg>>2)+4*h.
      // Lane covers 16 rows x 2 nt = 32 n; partner lane (l^32) covers the other 32.
      float attp[2] = {0.f, 0.f};
      #pragma unroll
      for (int nt = 0; nt < 2; ++nt) {
        #pragma unroll
        for (int r = 0; r < 16; ++r) {
          int n = wave * 64 + nt * 32 + (r & 3) + 8 * (r >> 2) + 4 * h;
          float cc = c_lds[n], ww = w_lds[n];
          #pragma unroll
          for (int st = 0; st < 2; ++st)
            attp[st] += fmaxf(acc2[nt][st][r] + cc, 0.f) * ww;
        }
      }
      #pragma unroll
      for (int st = 0; st < 2; ++st)
        attp[st] += __shfl_xor(attp[st], 32, 64);
      if (h == 0) {
        red[wave][l31]      = attp[0];       // seq = l31
        red[wave][32 + l31] = attp[1];       // seq = 32 + l31
      }
    } else if (i < 7) {
      STAGE_HALF(ci + 1, (i + 1) & 1, 0);
    }
    barrier_lgkm();

    // ============ phase 2a: softmax + pw partials  ||  stage half 1 ============
    if (!is_stage) {
      float av = 0.f;
      #pragma unroll
      for (int cw = 0; cw < 8; ++cw) av += red[cw][lane];
      float m = av;
      #pragma unroll
      for (int off = 32; off >= 1; off >>= 1) m = fmaxf(m, __shfl_xor(m, off, 64));
      float p = expf(av - m);                // row = lane
      if (wave == 0) {
        att_out[b * 4096 + (ci & 63) * 64 + lane] = av;  // b_att omitted: cancels in softmax
        if (lane == 0) m_out[ci] = m;
      }
      // pw: wave w owns s-rows w*8..w*8+7; lane reads full permuted row slice (conflict-free)
      float acc8[8] = {0.f, 0.f, 0.f, 0.f, 0.f, 0.f, 0.f, 0.f};
      #pragma unroll
      for (int j = 0; j < 8; ++j) {
        int s = wave * 8 + j;
        float ps = __shfl(p, s, 64);
        u32x4 u = *(const u32x4*)(Ab + s * 1024 + ((lane * 16) ^ ((s & 7) << 4)));
        acc8[0] += ps * lo_bf(u[0]); acc8[1] += ps * hi_bf(u[0]);
        acc8[2] += ps * lo_bf(u[1]); acc8[3] += ps * hi_bf(u[1]);
        acc8[4] += ps * lo_bf(u[2]); acc8[5] += ps * hi_bf(u[2]);
        acc8[6] += ps * lo_bf(u[3]); acc8[7] += ps * hi_bf(u[3]);
      }
      #pragma unroll
      for (int q = 0; q < 8; ++q)
        red2[(wave * 8 + q) * 72 + lane] = acc8[q];      // cols lane*8+q, s-oct = wave
    } else if (i < 7) {
      STAGE_HALF(ci + 1, (i + 1) & 1, 1);
    }
    barrier_lgkm();

    // ============ phase 2b: combine pw partials across waves, store ============
    if (tid < 512) {
      int lw = tid >> 3, q = tid & 7;        // col = lw*8 + q
      float s = 0.f;
      #pragma unroll
      for (int w = 0; w < 8; ++w) s += red2[(w * 8 + q) * 72 + lw];
      pw_out[ci * 512 + lw * 8 + q] = s;
    }
    barrier_lgkm();
  }
}

// ---------- finalize: per-batch global softmax + rescaled partial-sum reduction ----------
__global__ void finalize(const float* __restrict__ att, const float* __restrict__ m_blk,
                         const float* __restrict__ pw, float* __restrict__ out) {
  const int bg = blockIdx.x;                 // 128 blocks = 32 b x 4 groups
  const int b = bg >> 2, g = bg & 3;
  const int tid = threadIdx.x;               // 256
  const int wave = tid >> 6, lane = tid & 63;
  __shared__ float wred[4];
  __shared__ float zred[4];
  __shared__ float fac[64];

  float v[16];
  float mx = -3.4e38f;
  #pragma unroll
  for (int i = 0; i < 16; ++i) {
    v[i] = att[b * 4096 + i * 256 + tid];
    mx = fmaxf(mx, v[i]);
  }
  #pragma unroll
  for (int off = 32; off >= 1; off >>= 1) mx = fmaxf(mx, __shfl_xor(mx, off, 64));
  if (lane == 0) wred[wave] = mx;
  __syncthreads();
  mx = fmaxf(fmaxf(wred[0], wred[1]), fmaxf(wred[2], wred[3]));

  float z = 0.f;
  #pragma unroll
  for (int i = 0; i < 16; ++i) { v[i] = expf(v[i] - mx); z += v[i]; }
  #pragma unroll
  for (int off = 32; off >= 1; off >>= 1) z += __shfl_xor(z, off, 64);
  if (lane == 0) zred[wave] = z;
  __syncthreads();
  z = zred[0] + zred[1] + zred[2] + zred[3];
  float invZ = 1.f / z;

  #pragma unroll
  for (int i = 0; i < 4; ++i) {
    int ii = g * 4 + i;
    out[16384 + b * 4096 + ii * 256 + tid] = v[ii] * invZ;   // prob (this block's quarter)
  }

  if (tid < 64) fac[tid] = expf(m_blk[b * 64 + tid] - mx) * invZ;
  __syncthreads();

  int col = g * 128 + (tid >> 1);
  int h = tid & 1;
  float w0 = 0.f;
  #pragma unroll 8
  for (int s = h * 32; s < h * 32 + 32; ++s)
    w0 += fac[s] * pw[(b * 64 + s) * 512 + col];
  w0 += __shfl_xor(w0, 1, 64);
  if (h == 0) out[b * 512 + col] = w0;                       // weighted
}

extern "C" void kernel_launch(void* const* d_in, const int* in_sizes, int n_in,
                              void* d_out, int out_size, void* d_ws, size_t ws_size,
                              hipStream_t stream) {
  const float* input = (const float*)d_in[0];
  const float* dec_h = (const float*)d_in[1];
  const float* W_enc = (const float*)d_in[2];
  const float* b_enc = (const float*)d_in[3];
  const float* W_dec = (const float*)d_in[4];
  const float* b_dec = (const float*)d_in[5];
  const float* w_att = (const float*)d_in[6];
  // d_in[7] = b_att: constant shift of logits, cancels in softmax.
  float* out = (float*)d_out;

  char* ws = (char*)d_ws;
  unsigned short* Wf = (unsigned short*)(ws);           // 512 KB  A-fragment-ordered bf16 W_enc^T
  float* cpart = (float*)(ws + 524288);                 // 256 KB  dec_att partials [4][32][512]
  float* att   = (float*)(ws + 786432);                 // 512 KB  logits [32][4096]
  float* m_b   = (float*)(ws + 1310720);                // 8 KB    per-chunk max [2048]
  float* pw    = (float*)(ws + 1318912);                // 4 MB    partial weighted [2048][512]

  hipLaunchKernelGGL(prep_w, dim3(128), dim3(256), 0, stream, W_enc, Wf);
  hipLaunchKernelGGL(prep_c, dim3(128), dim3(512), 0, stream, dec_h, W_dec, b_dec, b_enc, cpart);
  hipLaunchKernelGGL(attn_main, dim3(256), dim3(1024), 0, stream, input, Wf, cpart, w_att, att, m_b, pw);
  hipLaunchKernelGGL(finalize, dim3(128), dim3(256), 0, stream, att, m_b, pw, out);
}